// Round 13
// baseline (2707.898 us; speedup 1.0000x reference)
//
#include <hip/hip_runtime.h>
#include <math.h>

#define S_LEN 4096
#define DMODEL 768
#define NHEAD 12
#define DHEAD 64
#define FFDIM 3072
#define NLAYER 12
#define WIN 256
#define QKVN 2304

typedef __bf16 bf16x8 __attribute__((ext_vector_type(8)));
typedef unsigned short u16x8 __attribute__((ext_vector_type(8)));
typedef unsigned short u16x4 __attribute__((ext_vector_type(4)));
typedef float f32x4 __attribute__((ext_vector_type(4)));
typedef float f32x16 __attribute__((ext_vector_type(16)));

__device__ inline unsigned short f2bf(float f) {
    unsigned int u = __float_as_uint(f);
    u += 0x7fff + ((u >> 16) & 1);
    return (unsigned short)(u >> 16);
}

__device__ inline void gload16(const void* g, void* l) {
    __builtin_amdgcn_global_load_lds((const __attribute__((address_space(1))) void*)g,
                                     (__attribute__((address_space(3))) void*)l, 16, 0, 0);
}

// ---------------- LayerNorm (wave-per-row, shuffle-only reduce; R10-proven) ----------------
__global__ __launch_bounds__(256) void ln_kernel(const float* __restrict__ in,
                                                 const float* __restrict__ s,
                                                 const float* __restrict__ b,
                                                 float* __restrict__ out,
                                                 unsigned short* __restrict__ outb) {
    const int wv = threadIdx.x >> 6, lane = threadIdx.x & 63;
    const int row = blockIdx.x * 4 + wv;
    const float* p = in + (size_t)row * DMODEL;
    const int c = lane * 4;
    float4 v0 = *(const float4*)&p[c];
    float4 v1 = *(const float4*)&p[c + 256];
    float4 v2 = *(const float4*)&p[c + 512];
    float sum = v0.x + v0.y + v0.z + v0.w + v1.x + v1.y + v1.z + v1.w
              + v2.x + v2.y + v2.z + v2.w;
    float sq  = v0.x*v0.x + v0.y*v0.y + v0.z*v0.z + v0.w*v0.w
              + v1.x*v1.x + v1.y*v1.y + v1.z*v1.z + v1.w*v1.w
              + v2.x*v2.x + v2.y*v2.y + v2.z*v2.z + v2.w*v2.w;
    #pragma unroll
    for (int off = 32; off; off >>= 1) {
        sum += __shfl_xor(sum, off);
        sq  += __shfl_xor(sq, off);
    }
    const float mu = sum * (1.0f / DMODEL);
    const float var = sq * (1.0f / DMODEL) - mu * mu;
    const float rs = rsqrtf(var + 1e-5f);
    float* o = out + (size_t)row * DMODEL;
    unsigned short* ob = outb + (size_t)row * DMODEL;
    #pragma unroll
    for (int seg = 0; seg < 3; ++seg) {
        const int cc = c + seg * 256;
        float4 v = (seg == 0) ? v0 : (seg == 1) ? v1 : v2;
        float4 sv = *(const float4*)&s[cc];
        float4 bv = *(const float4*)&b[cc];
        float4 r;
        r.x = (v.x - mu) * rs * sv.x + bv.x;
        r.y = (v.y - mu) * rs * sv.y + bv.y;
        r.z = (v.z - mu) * rs * sv.z + bv.z;
        r.w = (v.w - mu) * rs * sv.w + bv.w;
        *(float4*)&o[cc] = r;
        u16x4 pk;
        pk[0] = f2bf(r.x); pk[1] = f2bf(r.y); pk[2] = f2bf(r.z); pk[3] = f2bf(r.w);
        *(u16x4*)&ob[cc] = pk;
    }
}

// Fused split-K combine + residual + bias + LayerNorm (R11-proven).
__global__ __launch_bounds__(256) void ln2_kernel(const float* __restrict__ p1,
                                                  const float* __restrict__ p2,
                                                  const float* __restrict__ bias,
                                                  const float* __restrict__ xres,
                                                  const float* __restrict__ s,
                                                  const float* __restrict__ b,
                                                  float* __restrict__ outx,
                                                  unsigned short* __restrict__ outxb) {
    const int wv = threadIdx.x >> 6, lane = threadIdx.x & 63;
    const int row = blockIdx.x * 4 + wv;
    const size_t ro = (size_t)row * DMODEL;
    const int c = lane * 4;
    float4 vv[3];
    float sum = 0.f, sq = 0.f;
    #pragma unroll
    for (int seg = 0; seg < 3; ++seg) {
        const int cc = c + seg * 256;
        float4 a1 = *(const float4*)&p1[ro + cc];
        float4 a2 = *(const float4*)&p2[ro + cc];
        float4 bb = *(const float4*)&bias[cc];
        float4 xr = *(const float4*)&xres[ro + cc];
        float4 v;
        v.x = a1.x + a2.x + bb.x + xr.x;
        v.y = a1.y + a2.y + bb.y + xr.y;
        v.z = a1.z + a2.z + bb.z + xr.z;
        v.w = a1.w + a2.w + bb.w + xr.w;
        vv[seg] = v;
        sum += v.x + v.y + v.z + v.w;
        sq  += v.x*v.x + v.y*v.y + v.z*v.z + v.w*v.w;
    }
    #pragma unroll
    for (int off = 32; off; off >>= 1) {
        sum += __shfl_xor(sum, off);
        sq  += __shfl_xor(sq, off);
    }
    const float mu = sum * (1.0f / DMODEL);
    const float var = sq * (1.0f / DMODEL) - mu * mu;
    const float rs = rsqrtf(var + 1e-5f);
    #pragma unroll
    for (int seg = 0; seg < 3; ++seg) {
        const int cc = c + seg * 256;
        float4 v = vv[seg];
        float4 sv = *(const float4*)&s[cc];
        float4 bv = *(const float4*)&b[cc];
        float4 r;
        r.x = (v.x - mu) * rs * sv.x + bv.x;
        r.y = (v.y - mu) * rs * sv.y + bv.y;
        r.z = (v.z - mu) * rs * sv.z + bv.z;
        r.w = (v.w - mu) * rs * sv.w + bv.w;
        *(float4*)&outx[ro + cc] = r;
        u16x4 pk;
        pk[0] = f2bf(r.x); pk[1] = f2bf(r.y); pk[2] = f2bf(r.z); pk[3] = f2bf(r.w);
        *(u16x4*)&outxb[ro + cc] = pk;
    }
}

__device__ inline void block_reduce2(float& sum, float& sq) {
    #pragma unroll
    for (int off = 32; off; off >>= 1) {
        sum += __shfl_xor(sum, off);
        sq  += __shfl_xor(sq, off);
    }
    __shared__ float red[8];
    int wid = threadIdx.x >> 6, lane = threadIdx.x & 63;
    if (lane == 0) { red[wid] = sum; red[wid + 4] = sq; }
    __syncthreads();
    sum = red[0] + red[1] + red[2] + red[3];
    sq  = red[4] + red[5] + red[6] + red[7];
    __syncthreads();
}

__global__ __launch_bounds__(256) void embed_ln_kernel(const int* __restrict__ ids,
                                                       const float* __restrict__ wemb,
                                                       const float* __restrict__ pemb,
                                                       const float* __restrict__ s,
                                                       const float* __restrict__ b,
                                                       float* __restrict__ out,
                                                       unsigned short* __restrict__ outb) {
    int row = blockIdx.x, tid = threadIdx.x;
    int id = ids[row];
    const float* wp = wemb + (size_t)id * DMODEL;
    const float* pp = pemb + (size_t)(row + 2) * DMODEL;
    float v0 = wp[tid] + pp[tid];
    float v1 = wp[tid + 256] + pp[tid + 256];
    float v2 = wp[tid + 512] + pp[tid + 512];
    float sum = v0 + v1 + v2;
    float sq  = v0 * v0 + v1 * v1 + v2 * v2;
    block_reduce2(sum, sq);
    float mu = sum * (1.0f / DMODEL);
    float var = sq * (1.0f / DMODEL) - mu * mu;
    float rs = rsqrtf(var + 1e-5f);
    float* o = out + (size_t)row * DMODEL;
    unsigned short* ob = outb + (size_t)row * DMODEL;
    float r0 = (v0 - mu) * rs * s[tid]       + b[tid];
    float r1 = (v1 - mu) * rs * s[tid + 256] + b[tid + 256];
    float r2 = (v2 - mu) * rs * s[tid + 512] + b[tid + 512];
    o[tid] = r0; o[tid + 256] = r1; o[tid + 512] = r2;
    ob[tid] = f2bf(r0); ob[tid + 256] = f2bf(r1); ob[tid + 512] = f2bf(r2);
}

// ---------------- merged per-layer weight transpose + cvt (vectorized) ----------------
__global__ __launch_bounds__(256) void transpose_all(const float* __restrict__ wq,
                                                     const float* __restrict__ wk,
                                                     const float* __restrict__ wv,
                                                     const float* __restrict__ wo,
                                                     const float* __restrict__ w1,
                                                     const float* __restrict__ w2,
                                                     unsigned short* __restrict__ dq,
                                                     unsigned short* __restrict__ dk,
                                                     unsigned short* __restrict__ dv,
                                                     unsigned short* __restrict__ dwo,
                                                     unsigned short* __restrict__ d1,
                                                     unsigned short* __restrict__ d2) {
    const int id = blockIdx.x;
    const float* src; unsigned short* dst; int C, R, bx, by;
    if (id < 2304) {
        const int m = id / 576, t2 = id % 576;
        src = (m == 0) ? wq : (m == 1) ? wk : (m == 2) ? wv : wo;
        dst = (m == 0) ? dq : (m == 1) ? dk : (m == 2) ? dv : dwo;
        R = 768; C = 768; bx = (t2 % 24) * 32; by = (t2 / 24) * 32;
    } else if (id < 4608) {
        const int t2 = id - 2304;
        src = w1; dst = d1; R = 768; C = 3072;
        bx = (t2 % 96) * 32; by = (t2 / 96) * 32;
    } else {
        const int t2 = id - 4608;
        src = w2; dst = d2; R = 3072; C = 768;
        bx = (t2 % 24) * 32; by = (t2 / 24) * 32;
    }
    __shared__ float tile[32][33];
    const int t = threadIdx.x;
    const int lrow = t >> 3;
    const int lcol = (t & 7) * 4;
    float4 v = *(const float4*)&src[(size_t)(by + lrow) * C + bx + lcol];
    tile[lrow][lcol]     = v.x;
    tile[lrow][lcol + 1] = v.y;
    tile[lrow][lcol + 2] = v.z;
    tile[lrow][lcol + 3] = v.w;
    __syncthreads();
    const int c  = t >> 3;
    const int rp = t & 7;
    unsigned int b0 = f2bf(tile[4 * rp][c]);
    unsigned int b1 = f2bf(tile[4 * rp + 1][c]);
    unsigned int b2 = f2bf(tile[4 * rp + 2][c]);
    unsigned int b3 = f2bf(tile[4 * rp + 3][c]);
    uint2 pk;
    pk.x = (b1 << 16) | b0;
    pk.y = (b3 << 16) | b2;
    *(uint2*)&dst[(size_t)(bx + c) * R + by + 4 * rp] = pk;
}

__global__ __launch_bounds__(256) void bias_concat(const float* __restrict__ bq,
                                                   const float* __restrict__ bk,
                                                   const float* __restrict__ bv,
                                                   float* __restrict__ out) {
    int l = blockIdx.x, t = threadIdx.x;
    for (int i = t; i < DMODEL; i += 256) {
        out[(size_t)l * QKVN + i]              = bq[(size_t)l * DMODEL + i];
        out[(size_t)l * QKVN + DMODEL + i]     = bk[(size_t)l * DMODEL + i];
        out[(size_t)l * QKVN + 2 * DMODEL + i] = bv[(size_t)l * DMODEL + i];
    }
}

// ---------------- bf16 MFMA GEMM — 32x32x16 shape ----------------
// C[M][N] = A[M][Kstride](cols kbase..+K) @ Bt[N][Kstride]^T
// Block 128x128, 4 waves 2x2, wave tile 64x64 = 2x2 MFMAs of 32x32.
// C/D layout (verified m74/m101): col=lane&31, row=(reg&3)+8*(reg>>2)+4*(lane>>5).
// MODE 1: bf16 out = acc+bias; 2: bf16 out = gelu(acc+bias); 3: fp32 partial @ z*M*N.
template<int MODE>
__global__ __launch_bounds__(256) void mfma_gemm(const unsigned short* __restrict__ A,
                                                 const unsigned short* __restrict__ Bt,
                                                 const float* __restrict__ bias,
                                                 void* __restrict__ Cout,
                                                 int M, int N, int K, int Kstride) {
    __shared__ unsigned short As[128 * 64];
    __shared__ unsigned short Bs[128 * 64];
    const int tid = threadIdx.x;
    const int wv = tid >> 6, lane = tid & 63;
    const int bm = blockIdx.x * 128, bn = blockIdx.y * 128;
    const size_t kbase = (size_t)blockIdx.z * K;
    const int wr = (wv >> 1) * 64, wc = (wv & 1) * 64;
    const int l31 = lane & 31, h5 = lane >> 5;

    f32x16 acc[2][2];
    #pragma unroll
    for (int m = 0; m < 2; ++m)
        #pragma unroll
        for (int n = 0; n < 2; ++n)
            #pragma unroll
            for (int e = 0; e < 16; ++e) acc[m][n][e] = 0.f;

    const int srow = tid >> 3;
    const int scol = (tid & 7) * 8;

    for (int k0 = 0; k0 < K; k0 += 64) {
        __syncthreads();
        #pragma unroll
        for (int c = 0; c < 4; ++c)
            gload16(A + (size_t)(bm + c * 32 + srow) * Kstride + kbase + k0 + scol,
                    (char*)As + c * 4096 + wv * 1024);
        #pragma unroll
        for (int c = 0; c < 4; ++c)
            gload16(Bt + (size_t)(bn + c * 32 + srow) * Kstride + kbase + k0 + scol,
                    (char*)Bs + c * 4096 + wv * 1024);
        __syncthreads();
        #pragma unroll
        for (int ks = 0; ks < 4; ++ks) {
            bf16x8 af[2], bfr[2];
            #pragma unroll
            for (int m = 0; m < 2; ++m)
                af[m] = *(const bf16x8*)(As + (wr + m * 32 + l31) * 64 + ks * 16 + h5 * 8);
            #pragma unroll
            for (int n = 0; n < 2; ++n)
                bfr[n] = *(const bf16x8*)(Bs + (wc + n * 32 + l31) * 64 + ks * 16 + h5 * 8);
            #pragma unroll
            for (int m = 0; m < 2; ++m)
                #pragma unroll
                for (int n = 0; n < 2; ++n)
                    acc[m][n] = __builtin_amdgcn_mfma_f32_32x32x16_bf16(af[m], bfr[n], acc[m][n], 0, 0, 0);
        }
    }

    const size_t zoff = (MODE == 3) ? (size_t)blockIdx.z * M * N : 0;
    #pragma unroll
    for (int m = 0; m < 2; ++m) {
        #pragma unroll
        for (int n = 0; n < 2; ++n) {
            const int col = bn + wc + n * 32 + l31;
            const float bb = (MODE == 3) ? 0.f : bias[col];
            #pragma unroll
            for (int r = 0; r < 16; ++r) {
                const int row = bm + wr + m * 32 + (r & 3) + 8 * (r >> 2) + 4 * h5;
                if (MODE == 3) {
                    ((float*)Cout)[zoff + (size_t)row * N + col] = acc[m][n][r];
                } else {
                    float v = acc[m][n][r] + bb;
                    if (MODE == 1) {
                        ((unsigned short*)Cout)[(size_t)row * N + col] = f2bf(v);
                    } else {
                        float gv = 0.5f * v * (1.0f + erff(v * 0.70710678118654752f));
                        ((unsigned short*)Cout)[(size_t)row * N + col] = f2bf(gv);
                    }
                }
            }
        }
    }
}

// ---------------- MFMA flash attention (sliding window) ----------------
// R12 structure + interior-chunk fast path: chunks c in [1,7] with kc>=0 and
// kc+64<=S are provably fully in-band (max|key-qa| = 64c-193 <= 255), so the
// band test and bounds clamp reduce to the mask test alone.
__global__ __launch_bounds__(256) void attn_mfma(const unsigned short* __restrict__ qkv,
                                                 const int* __restrict__ msk,
                                                 unsigned short* __restrict__ aout) {
    __shared__ unsigned short Ks[64 * 64];
    __shared__ unsigned short Vt[64 * 64];
    __shared__ unsigned short Ps[4][16 * 64];
    const int tid = threadIdx.x;
    const int wv = tid >> 6, lane = tid & 63;
    const int l15 = lane & 15, g = lane >> 4;
    const int h = blockIdx.y;
    const int q0 = blockIdx.x * 64;

    const int qrow = q0 + wv * 16 + l15;
    bf16x8 qf[2];
    #pragma unroll
    for (int kk = 0; kk < 2; ++kk)
        qf[kk] = *(const bf16x8*)(qkv + (size_t)qrow * QKVN + h * 64 + kk * 32 + g * 8);

    f32x4 o[4];
    #pragma unroll
    for (int n = 0; n < 4; ++n)
        #pragma unroll
        for (int e = 0; e < 4; ++e) o[n][e] = 0.f;
    float mst[4] = {-3e38f, -3e38f, -3e38f, -3e38f};
    float lst[4] = {0.f, 0.f, 0.f, 0.f};

    const int srow = tid >> 3;
    const int scol = (tid & 7) * 8;
    const int xr  = (l15 & 7) << 3;
    const int kg4 = (tid >> 4) * 4;
    const int dg4 = (tid & 15) * 4;

    for (int c = 0; c < 9; ++c) {
        const int kc = q0 - 256 + c * 64;
        if (kc + 64 <= 0 || kc >= S_LEN) continue;   // fully masked chunk: exact no-op
        const bool fast = (kc >= 0) && (kc + 64 <= S_LEN) && (c >= 1) && (c <= 7);
        __syncthreads();
        #pragma unroll
        for (int cc = 0; cc < 2; ++cc) {
            const int r = cc * 32 + srow;
            int krow = min(max(kc + r, 0), S_LEN - 1);
            gload16(qkv + (size_t)krow * QKVN + DMODEL + h * 64 + (scol ^ ((r & 7) << 3)),
                    (char*)Ks + cc * 4096 + wv * 1024);
        }
        {
            u16x4 vr[4];
            #pragma unroll
            for (int j = 0; j < 4; ++j) {
                int vrow = min(max(kc + kg4 + j, 0), S_LEN - 1);
                vr[j] = *(const u16x4*)(qkv + (size_t)vrow * QKVN + 2 * DMODEL + h * 64 + dg4);
            }
            #pragma unroll
            for (int i = 0; i < 4; ++i) {
                const int d = dg4 + i;
                const int f = ((d >> 3) ^ d) & 7;
                u16x4 w;
                w[0] = vr[0][i]; w[1] = vr[1][i]; w[2] = vr[2][i]; w[3] = vr[3][i];
                *(u16x4*)(Vt + d * 64 + (kg4 ^ (f << 3))) = w;
            }
        }
        __syncthreads();

        f32x4 s[4];
        #pragma unroll
        for (int n = 0; n < 4; ++n)
            #pragma unroll
            for (int e = 0; e < 4; ++e) s[n][e] = 0.f;
        __builtin_amdgcn_s_setprio(1);
        #pragma unroll
        for (int kk = 0; kk < 2; ++kk) {
            #pragma unroll
            for (int n = 0; n < 4; ++n) {
                bf16x8 kf = *(const bf16x8*)(Ks + (n * 16 + l15) * 64 + ((kk * 32 + g * 8) ^ xr));
                s[n] = __builtin_amdgcn_mfma_f32_16x16x32_bf16(qf[kk], kf, s[n], 0, 0, 0);
            }
        }
        __builtin_amdgcn_s_setprio(0);

        float pv[4][4];
        const int qbase = q0 + wv * 16 + g * 4;
        if (fast) {
            #pragma unroll
            for (int n = 0; n < 4; ++n) {
                const int key = kc + n * 16 + l15;
                const int mv = msk[key];
                #pragma unroll
                for (int r = 0; r < 4; ++r)
                    pv[n][r] = mv ? s[n][r] * 0.125f : -1e9f;
            }
        } else {
            #pragma unroll
            for (int n = 0; n < 4; ++n) {
                const int key = kc + n * 16 + l15;
                const bool kin = (key >= 0) && (key < S_LEN);
                const int mv = kin ? msk[key] : 0;
                #pragma unroll
                for (int r = 0; r < 4; ++r) {
                    const int qa = qbase + r;
                    const bool valid = (mv != 0) && (abs(key - qa) <= WIN);
                    pv[n][r] = valid ? s[n][r] * 0.125f : -1e9f;
                }
            }
        }
        float scold[4];
        #pragma unroll
        for (int r = 0; r < 4; ++r) {
            float mx = fmaxf(fmaxf(pv[0][r], pv[1][r]), fmaxf(pv[2][r], pv[3][r]));
            mx = fmaxf(mx, __shfl_xor(mx, 1));
            mx = fmaxf(mx, __shfl_xor(mx, 2));
            mx = fmaxf(mx, __shfl_xor(mx, 4));
            mx = fmaxf(mx, __shfl_xor(mx, 8));
            const float nm = fmaxf(mst[r], mx);
            scold[r] = __expf(mst[r] - nm);
            float sum = 0.f;
            #pragma unroll
            for (int n = 0; n < 4; ++n) { pv[n][r] = __expf(pv[n][r] - nm); sum += pv[n][r]; }
            sum += __shfl_xor(sum, 1); sum += __shfl_xor(sum, 2);
            sum += __shfl_xor(sum, 4); sum += __shfl_xor(sum, 8);
            lst[r] = lst[r] * scold[r] + sum;
            mst[r] = nm;
        }
        #pragma unroll
        for (int n = 0; n < 4; ++n)
            #pragma unroll
            for (int r = 0; r < 4; ++r)
                o[n][r] *= scold[r];

        #pragma unroll
        for (int n = 0; n < 4; ++n)
            #pragma unroll
            for (int r = 0; r < 4; ++r) {
                const int ql = g * 4 + r;
                Ps[wv][ql * 64 + ((n * 16 + l15) ^ ((ql & 7) << 3))] = f2bf(pv[n][r]);
            }

        __builtin_amdgcn_s_setprio(1);
        #pragma unroll
        for (int kk = 0; kk < 2; ++kk) {
            bf16x8 pf = *(const bf16x8*)(Ps[wv] + l15 * 64 + ((kk * 32 + g * 8) ^ xr));
            #pragma unroll
            for (int nd = 0; nd < 4; ++nd) {
                const int d = nd * 16 + l15;
                const int xv = (((nd * 2 + (l15 >> 3)) & 7) ^ (l15 & 7)) << 3;
                bf16x8 vf = *(const bf16x8*)(Vt + d * 64 + ((kk * 32 + g * 8) ^ xv));
                o[nd] = __builtin_amdgcn_mfma_f32_16x16x32_bf16(pf, vf, o[nd], 0, 0, 0);
            }
        }
        __builtin_amdgcn_s_setprio(0);
    }

    #pragma unroll
    for (int r = 0; r < 4; ++r) {
        const float inv = 1.0f / lst[r];
        const int qa = q0 + wv * 16 + g * 4 + r;
        #pragma unroll
        for (int nd = 0; nd < 4; ++nd)
            aout[(size_t)qa * DMODEL + h * 64 + nd * 16 + l15] = f2bf(o[nd][r] * inv);
    }
}

// ---------------- Head MLP (parallelized) ----------------
__global__ __launch_bounds__(256) void head1_kernel(const int* __restrict__ ids,
                                                    const float* __restrict__ x,
                                                    const float* __restrict__ w1,
                                                    const float* __restrict__ b1,
                                                    float* __restrict__ z1) {
    const int tid = threadIdx.x;
    __shared__ int sred[256];
    int loc = -1;
    for (int i = tid; i < S_LEN; i += 256)
        if (ids[i] == 2) loc = i;
    sred[tid] = loc;
    __syncthreads();
    for (int s2 = 128; s2; s2 >>= 1) {
        if (tid < s2) sred[tid] = max(sred[tid], sred[tid + s2]);
        __syncthreads();
    }
    const int sep = sred[0] < 0 ? (S_LEN - 1) : sred[0];

    __shared__ float emb[DMODEL];
    for (int d = tid; d < DMODEL; d += 256) emb[d] = x[(size_t)sep * DMODEL + d];
    __syncthreads();

    const int o = blockIdx.x * 64 + (tid & 63);
    const int chunk = tid >> 6;
    float s = 0.f;
    const int d0 = chunk * 192;
    for (int d = d0; d < d0 + 192; ++d)
        s += emb[d] * w1[(size_t)d * 512 + o];
    __shared__ float part[4][64];
    part[chunk][tid & 63] = s;
    __syncthreads();
    if (chunk == 0) {
        float v = part[0][tid] + part[1][tid] + part[2][tid] + part[3][tid] + b1[o];
        z1[o] = fmaxf(v, 0.f);
    }
}

__global__ __launch_bounds__(256) void head2_kernel(const float* __restrict__ z1,
                                                    const float* __restrict__ w2,
                                                    const float* __restrict__ b2,
                                                    const float* __restrict__ w3,
                                                    const float* __restrict__ b3,
                                                    float* __restrict__ out) {
    const int tid = threadIdx.x;
    __shared__ float z1s[512];
    for (int i = tid; i < 512; i += 256) z1s[i] = z1[i];
    __syncthreads();
    float s = b2[tid];
    for (int d = 0; d < 512; ++d) s += z1s[d] * w2[(size_t)d * 256 + tid];
    float z2 = fmaxf(s, 0.f);
    __shared__ float fred[256];
    fred[tid] = z2 * w3[tid];
    __syncthreads();
    for (int s2 = 128; s2; s2 >>= 1) {
        if (tid < s2) fred[tid] += fred[tid + s2];
        __syncthreads();
    }
    if (tid == 0) out[0] = tanhf(fred[0] + b3[0]);
}

// ---------------- launch ----------------

extern "C" void kernel_launch(void* const* d_in, const int* in_sizes, int n_in,
                              void* d_out, int out_size, void* d_ws, size_t ws_size,
                              hipStream_t stream) {
    const int*   ids      = (const int*)d_in[0];
    const int*   amask    = (const int*)d_in[1];
    const float* word_emb = (const float*)d_in[2];
    const float* pos_emb  = (const float*)d_in[3];
    const float* emb_s    = (const float*)d_in[4];
    const float* emb_b    = (const float*)d_in[5];
    const float* Wq = (const float*)d_in[6];
    const float* bq = (const float*)d_in[7];
    const float* Wk = (const float*)d_in[8];
    const float* bk = (const float*)d_in[9];
    const float* Wv = (const float*)d_in[10];
    const float* bv = (const float*)d_in[11];
    const float* Wo = (const float*)d_in[12];
    const float* bo = (const float*)d_in[13];
    const float* l1s = (const float*)d_in[14];
    const float* l1b = (const float*)d_in[15];
    const float* W1 = (const float*)d_in[16];
    const float* b1 = (const float*)d_in[17];
    const float* W2 = (const float*)d_in[18];
    const float* b2 = (const float*)d_in[19];
    const float* l2s = (const float*)d_in[20];
    const float* l2b = (const float*)d_in[21];
    const float* h1w = (const float*)d_in[22];
    const float* h1b = (const float*)d_in[23];
    const float* h2w = (const float*)d_in[24];
    const float* h2b = (const float*)d_in[25];
    const float* h3w = (const float*)d_in[26];
    const float* h3b = (const float*)d_in[27];

    char* ws = (char*)d_ws;
    float* x          = (float*)(ws);                              // 12.58 MB
    unsigned short* xb   = (unsigned short*)(ws + 25165824);       // 6.29 MB
    unsigned short* qkv  = (unsigned short*)(ws + 31457280);       // 18.87 MB
    unsigned short* a    = (unsigned short*)(ws + 50331648);       // 6.29 MB
    unsigned short* hb   = (unsigned short*)(ws + 56623104);       // 25.17 MB
    unsigned short* WqkvT= (unsigned short*)(ws + 81788928);       // 3.54 MB
    unsigned short* WoT  = (unsigned short*)(ws + 85327872);       // 1.18 MB
    unsigned short* W1T  = (unsigned short*)(ws + 86507520);       // 4.72 MB
    unsigned short* W2T  = (unsigned short*)(ws + 91226112);       // 4.72 MB
    float* biascat       = (float*)(ws + 95944704);                // 0.11 MB
    float* z1ws          = (float*)(ws + 96055296);                // 2 KB
    float* p12           = (float*)(ws + 100663296);               // 2x 12.58 MB contiguous split-K partials
    float* p12b          = p12 + (size_t)S_LEN * DMODEL;

    bias_concat<<<NLAYER, 256, 0, stream>>>(bq, bk, bv, biascat);
    embed_ln_kernel<<<S_LEN, 256, 0, stream>>>(ids, word_emb, pos_emb, emb_s, emb_b, x, xb);

    const size_t dd = (size_t)DMODEL * DMODEL;
    const size_t df = (size_t)DMODEL * FFDIM;

    for (int l = 0; l < NLAYER; ++l) {
        transpose_all<<<6912, 256, 0, stream>>>(Wq + l * dd, Wk + l * dd, Wv + l * dd, Wo + l * dd,
                                                W1 + l * df, W2 + l * df,
                                                WqkvT, WqkvT + dd, WqkvT + 2 * dd, WoT, W1T, W2T);

        mfma_gemm<1><<<dim3(32, 18), 256, 0, stream>>>(xb, WqkvT, biascat + (size_t)l * QKVN,
                                                       qkv, S_LEN, QKVN, DMODEL, DMODEL);
        attn_mfma<<<dim3(S_LEN / 64, NHEAD), 256, 0, stream>>>(qkv, amask, a);

        mfma_gemm<3><<<dim3(32, 6, 2), 256, 0, stream>>>(a, WoT, nullptr,
                                                         p12, S_LEN, DMODEL, 384, DMODEL);
        ln2_kernel<<<S_LEN / 4, 256, 0, stream>>>(p12, p12b, bo + (size_t)l * DMODEL, x,
                                                  l1s + (size_t)l * DMODEL, l1b + (size_t)l * DMODEL,
                                                  x, xb);

        mfma_gemm<2><<<dim3(32, 24), 256, 0, stream>>>(xb, W1T, b1 + (size_t)l * FFDIM,
                                                       hb, S_LEN, FFDIM, DMODEL, DMODEL);
        mfma_gemm<3><<<dim3(32, 6, 2), 256, 0, stream>>>(hb, W2T, nullptr,
                                                         p12, S_LEN, DMODEL, 1536, FFDIM);
        ln2_kernel<<<S_LEN / 4, 256, 0, stream>>>(p12, p12b, b2 + (size_t)l * DMODEL, x,
                                                  l2s + (size_t)l * DMODEL, l2b + (size_t)l * DMODEL,
                                                  x, xb);
    }

    head1_kernel<<<8, 256, 0, stream>>>(ids, x, h1w, h1b, z1ws);
    head2_kernel<<<1, 256, 0, stream>>>(z1ws, h2w, h2b, h3w, h3b, (float*)d_out);
}

// Round 14
// 2453.624 us; speedup vs baseline: 1.1036x; 1.1036x over previous
//
#include <hip/hip_runtime.h>
#include <math.h>

#define S_LEN 4096
#define DMODEL 768
#define NHEAD 12
#define DHEAD 64
#define FFDIM 3072
#define NLAYER 12
#define WIN 256
#define QKVN 2304

typedef __bf16 bf16x8 __attribute__((ext_vector_type(8)));
typedef unsigned short u16x8 __attribute__((ext_vector_type(8)));
typedef unsigned short u16x4 __attribute__((ext_vector_type(4)));
typedef float f32x4 __attribute__((ext_vector_type(4)));

__device__ inline unsigned short f2bf(float f) {
    unsigned int u = __float_as_uint(f);
    u += 0x7fff + ((u >> 16) & 1);
    return (unsigned short)(u >> 16);
}

__device__ inline void gload16(const void* g, void* l) {
    __builtin_amdgcn_global_load_lds((const __attribute__((address_space(1))) void*)g,
                                     (__attribute__((address_space(3))) void*)l, 16, 0, 0);
}

// ---------------- LayerNorm (wave-per-row, shuffle-only reduce; R10-proven) ----------------
__global__ __launch_bounds__(256) void ln_kernel(const float* __restrict__ in,
                                                 const float* __restrict__ s,
                                                 const float* __restrict__ b,
                                                 float* __restrict__ out,
                                                 unsigned short* __restrict__ outb) {
    const int wv = threadIdx.x >> 6, lane = threadIdx.x & 63;
    const int row = blockIdx.x * 4 + wv;
    const float* p = in + (size_t)row * DMODEL;
    const int c = lane * 4;
    float4 v0 = *(const float4*)&p[c];
    float4 v1 = *(const float4*)&p[c + 256];
    float4 v2 = *(const float4*)&p[c + 512];
    float sum = v0.x + v0.y + v0.z + v0.w + v1.x + v1.y + v1.z + v1.w
              + v2.x + v2.y + v2.z + v2.w;
    float sq  = v0.x*v0.x + v0.y*v0.y + v0.z*v0.z + v0.w*v0.w
              + v1.x*v1.x + v1.y*v1.y + v1.z*v1.z + v1.w*v1.w
              + v2.x*v2.x + v2.y*v2.y + v2.z*v2.z + v2.w*v2.w;
    #pragma unroll
    for (int off = 32; off; off >>= 1) {
        sum += __shfl_xor(sum, off);
        sq  += __shfl_xor(sq, off);
    }
    const float mu = sum * (1.0f / DMODEL);
    const float var = sq * (1.0f / DMODEL) - mu * mu;
    const float rs = rsqrtf(var + 1e-5f);
    float* o = out + (size_t)row * DMODEL;
    unsigned short* ob = outb + (size_t)row * DMODEL;
    #pragma unroll
    for (int seg = 0; seg < 3; ++seg) {
        const int cc = c + seg * 256;
        float4 v = (seg == 0) ? v0 : (seg == 1) ? v1 : v2;
        float4 sv = *(const float4*)&s[cc];
        float4 bv = *(const float4*)&b[cc];
        float4 r;
        r.x = (v.x - mu) * rs * sv.x + bv.x;
        r.y = (v.y - mu) * rs * sv.y + bv.y;
        r.z = (v.z - mu) * rs * sv.z + bv.z;
        r.w = (v.w - mu) * rs * sv.w + bv.w;
        *(float4*)&o[cc] = r;
        u16x4 pk;
        pk[0] = f2bf(r.x); pk[1] = f2bf(r.y); pk[2] = f2bf(r.z); pk[3] = f2bf(r.w);
        *(u16x4*)&ob[cc] = pk;
    }
}

// Fused split-K combine + residual + bias + LayerNorm (R11-proven).
__global__ __launch_bounds__(256) void ln2_kernel(const float* __restrict__ p1,
                                                  const float* __restrict__ p2,
                                                  const float* __restrict__ bias,
                                                  const float* __restrict__ xres,
                                                  const float* __restrict__ s,
                                                  const float* __restrict__ b,
                                                  float* __restrict__ outx,
                                                  unsigned short* __restrict__ outxb) {
    const int wv = threadIdx.x >> 6, lane = threadIdx.x & 63;
    const int row = blockIdx.x * 4 + wv;
    const size_t ro = (size_t)row * DMODEL;
    const int c = lane * 4;
    float4 vv[3];
    float sum = 0.f, sq = 0.f;
    #pragma unroll
    for (int seg = 0; seg < 3; ++seg) {
        const int cc = c + seg * 256;
        float4 a1 = *(const float4*)&p1[ro + cc];
        float4 a2 = *(const float4*)&p2[ro + cc];
        float4 bb = *(const float4*)&bias[cc];
        float4 xr = *(const float4*)&xres[ro + cc];
        float4 v;
        v.x = a1.x + a2.x + bb.x + xr.x;
        v.y = a1.y + a2.y + bb.y + xr.y;
        v.z = a1.z + a2.z + bb.z + xr.z;
        v.w = a1.w + a2.w + bb.w + xr.w;
        vv[seg] = v;
        sum += v.x + v.y + v.z + v.w;
        sq  += v.x*v.x + v.y*v.y + v.z*v.z + v.w*v.w;
    }
    #pragma unroll
    for (int off = 32; off; off >>= 1) {
        sum += __shfl_xor(sum, off);
        sq  += __shfl_xor(sq, off);
    }
    const float mu = sum * (1.0f / DMODEL);
    const float var = sq * (1.0f / DMODEL) - mu * mu;
    const float rs = rsqrtf(var + 1e-5f);
    #pragma unroll
    for (int seg = 0; seg < 3; ++seg) {
        const int cc = c + seg * 256;
        float4 v = vv[seg];
        float4 sv = *(const float4*)&s[cc];
        float4 bv = *(const float4*)&b[cc];
        float4 r;
        r.x = (v.x - mu) * rs * sv.x + bv.x;
        r.y = (v.y - mu) * rs * sv.y + bv.y;
        r.z = (v.z - mu) * rs * sv.z + bv.z;
        r.w = (v.w - mu) * rs * sv.w + bv.w;
        *(float4*)&outx[ro + cc] = r;
        u16x4 pk;
        pk[0] = f2bf(r.x); pk[1] = f2bf(r.y); pk[2] = f2bf(r.z); pk[3] = f2bf(r.w);
        *(u16x4*)&outxb[ro + cc] = pk;
    }
}

__device__ inline void block_reduce2(float& sum, float& sq) {
    #pragma unroll
    for (int off = 32; off; off >>= 1) {
        sum += __shfl_xor(sum, off);
        sq  += __shfl_xor(sq, off);
    }
    __shared__ float red[8];
    int wid = threadIdx.x >> 6, lane = threadIdx.x & 63;
    if (lane == 0) { red[wid] = sum; red[wid + 4] = sq; }
    __syncthreads();
    sum = red[0] + red[1] + red[2] + red[3];
    sq  = red[4] + red[5] + red[6] + red[7];
    __syncthreads();
}

__global__ __launch_bounds__(256) void embed_ln_kernel(const int* __restrict__ ids,
                                                       const float* __restrict__ wemb,
                                                       const float* __restrict__ pemb,
                                                       const float* __restrict__ s,
                                                       const float* __restrict__ b,
                                                       float* __restrict__ out,
                                                       unsigned short* __restrict__ outb) {
    int row = blockIdx.x, tid = threadIdx.x;
    int id = ids[row];
    const float* wp = wemb + (size_t)id * DMODEL;
    const float* pp = pemb + (size_t)(row + 2) * DMODEL;
    float v0 = wp[tid] + pp[tid];
    float v1 = wp[tid + 256] + pp[tid + 256];
    float v2 = wp[tid + 512] + pp[tid + 512];
    float sum = v0 + v1 + v2;
    float sq  = v0 * v0 + v1 * v1 + v2 * v2;
    block_reduce2(sum, sq);
    float mu = sum * (1.0f / DMODEL);
    float var = sq * (1.0f / DMODEL) - mu * mu;
    float rs = rsqrtf(var + 1e-5f);
    float* o = out + (size_t)row * DMODEL;
    unsigned short* ob = outb + (size_t)row * DMODEL;
    float r0 = (v0 - mu) * rs * s[tid]       + b[tid];
    float r1 = (v1 - mu) * rs * s[tid + 256] + b[tid + 256];
    float r2 = (v2 - mu) * rs * s[tid + 512] + b[tid + 512];
    o[tid] = r0; o[tid + 256] = r1; o[tid + 512] = r2;
    ob[tid] = f2bf(r0); ob[tid + 256] = f2bf(r1); ob[tid + 512] = f2bf(r2);
}

// ---------------- merged per-layer weight transpose + cvt (vectorized) ----------------
__global__ __launch_bounds__(256) void transpose_all(const float* __restrict__ wq,
                                                     const float* __restrict__ wk,
                                                     const float* __restrict__ wv,
                                                     const float* __restrict__ wo,
                                                     const float* __restrict__ w1,
                                                     const float* __restrict__ w2,
                                                     unsigned short* __restrict__ dq,
                                                     unsigned short* __restrict__ dk,
                                                     unsigned short* __restrict__ dv,
                                                     unsigned short* __restrict__ dwo,
                                                     unsigned short* __restrict__ d1,
                                                     unsigned short* __restrict__ d2) {
    const int id = blockIdx.x;
    const float* src; unsigned short* dst; int C, R, bx, by;
    if (id < 2304) {
        const int m = id / 576, t2 = id % 576;
        src = (m == 0) ? wq : (m == 1) ? wk : (m == 2) ? wv : wo;
        dst = (m == 0) ? dq : (m == 1) ? dk : (m == 2) ? dv : dwo;
        R = 768; C = 768; bx = (t2 % 24) * 32; by = (t2 / 24) * 32;
    } else if (id < 4608) {
        const int t2 = id - 2304;
        src = w1; dst = d1; R = 768; C = 3072;
        bx = (t2 % 96) * 32; by = (t2 / 96) * 32;
    } else {
        const int t2 = id - 4608;
        src = w2; dst = d2; R = 3072; C = 768;
        bx = (t2 % 24) * 32; by = (t2 / 24) * 32;
    }
    __shared__ float tile[32][33];
    const int t = threadIdx.x;
    const int lrow = t >> 3;
    const int lcol = (t & 7) * 4;
    float4 v = *(const float4*)&src[(size_t)(by + lrow) * C + bx + lcol];
    tile[lrow][lcol]     = v.x;
    tile[lrow][lcol + 1] = v.y;
    tile[lrow][lcol + 2] = v.z;
    tile[lrow][lcol + 3] = v.w;
    __syncthreads();
    const int c  = t >> 3;
    const int rp = t & 7;
    unsigned int b0 = f2bf(tile[4 * rp][c]);
    unsigned int b1 = f2bf(tile[4 * rp + 1][c]);
    unsigned int b2 = f2bf(tile[4 * rp + 2][c]);
    unsigned int b3 = f2bf(tile[4 * rp + 3][c]);
    uint2 pk;
    pk.x = (b1 << 16) | b0;
    pk.y = (b3 << 16) | b2;
    *(uint2*)&dst[(size_t)(bx + c) * R + by + 4 * rp] = pk;
}

__global__ __launch_bounds__(256) void bias_concat(const float* __restrict__ bq,
                                                   const float* __restrict__ bk,
                                                   const float* __restrict__ bv,
                                                   float* __restrict__ out) {
    int l = blockIdx.x, t = threadIdx.x;
    for (int i = t; i < DMODEL; i += 256) {
        out[(size_t)l * QKVN + i]              = bq[(size_t)l * DMODEL + i];
        out[(size_t)l * QKVN + DMODEL + i]     = bk[(size_t)l * DMODEL + i];
        out[(size_t)l * QKVN + 2 * DMODEL + i] = bv[(size_t)l * DMODEL + i];
    }
}

// ---------------- bf16 MFMA GEMM (16x16x32, R12-proven) ----------------
// MODE 1: bf16 out = acc+bias; 2: bf16 out = gelu(acc+bias);
// MODE 3: split-K partial — raw fp32 acc to Cout + blockIdx.z*M*N.
template<int MODE>
__global__ __launch_bounds__(256) void mfma_gemm(const unsigned short* __restrict__ A,
                                                 const unsigned short* __restrict__ Bt,
                                                 const float* __restrict__ bias,
                                                 void* __restrict__ Cout,
                                                 int M, int N, int K, int Kstride) {
    __shared__ unsigned short As[128 * 64];
    __shared__ unsigned short Bs[128 * 64];
    const int tid = threadIdx.x;
    const int wv = tid >> 6, lane = tid & 63;
    const int bm = blockIdx.x * 128, bn = blockIdx.y * 128;
    const size_t kbase = (size_t)blockIdx.z * K;
    const int wr = (wv >> 1) * 64, wc = (wv & 1) * 64;
    const int l15 = lane & 15, g = lane >> 4;

    f32x4 acc[4][4];
    #pragma unroll
    for (int m = 0; m < 4; ++m)
        #pragma unroll
        for (int n = 0; n < 4; ++n)
            #pragma unroll
            for (int e = 0; e < 4; ++e) acc[m][n][e] = 0.f;

    const int srow = tid >> 3;
    const int scol = (tid & 7) * 8;

    for (int k0 = 0; k0 < K; k0 += 64) {
        __syncthreads();
        #pragma unroll
        for (int c = 0; c < 4; ++c)
            gload16(A + (size_t)(bm + c * 32 + srow) * Kstride + kbase + k0 + scol,
                    (char*)As + c * 4096 + wv * 1024);
        #pragma unroll
        for (int c = 0; c < 4; ++c)
            gload16(Bt + (size_t)(bn + c * 32 + srow) * Kstride + kbase + k0 + scol,
                    (char*)Bs + c * 4096 + wv * 1024);
        __syncthreads();
        #pragma unroll
        for (int kk = 0; kk < 2; ++kk) {
            bf16x8 af[4], bfr[4];
            #pragma unroll
            for (int m = 0; m < 4; ++m)
                af[m] = *(const bf16x8*)(As + (wr + m * 16 + l15) * 64 + kk * 32 + g * 8);
            #pragma unroll
            for (int n = 0; n < 4; ++n)
                bfr[n] = *(const bf16x8*)(Bs + (wc + n * 16 + l15) * 64 + kk * 32 + g * 8);
            #pragma unroll
            for (int m = 0; m < 4; ++m)
                #pragma unroll
                for (int n = 0; n < 4; ++n)
                    acc[m][n] = __builtin_amdgcn_mfma_f32_16x16x32_bf16(af[m], bfr[n], acc[m][n], 0, 0, 0);
        }
    }

    const size_t zoff = (MODE == 3) ? (size_t)blockIdx.z * M * N : 0;
    #pragma unroll
    for (int m = 0; m < 4; ++m) {
        const int row0 = bm + wr + m * 16 + g * 4;
        #pragma unroll
        for (int n = 0; n < 4; ++n) {
            const int col = bn + wc + n * 16 + l15;
            if (MODE == 3) {
                #pragma unroll
                for (int r = 0; r < 4; ++r)
                    ((float*)Cout)[zoff + (size_t)(row0 + r) * N + col] = acc[m][n][r];
            } else {
                const float bb = bias[col];
                #pragma unroll
                for (int r = 0; r < 4; ++r) {
                    float v = acc[m][n][r] + bb;
                    if (MODE == 1) {
                        ((unsigned short*)Cout)[(size_t)(row0 + r) * N + col] = f2bf(v);
                    } else {
                        float gv = 0.5f * v * (1.0f + erff(v * 0.70710678118654752f));
                        ((unsigned short*)Cout)[(size_t)(row0 + r) * N + col] = f2bf(gv);
                    }
                }
            }
        }
    }
}

// ---------------- MFMA flash attention (sliding window; R12 + interior fast path) ----------------
__global__ __launch_bounds__(256) void attn_mfma(const unsigned short* __restrict__ qkv,
                                                 const int* __restrict__ msk,
                                                 unsigned short* __restrict__ aout) {
    __shared__ unsigned short Ks[64 * 64];
    __shared__ unsigned short Vt[64 * 64];
    __shared__ unsigned short Ps[4][16 * 64];
    const int tid = threadIdx.x;
    const int wv = tid >> 6, lane = tid & 63;
    const int l15 = lane & 15, g = lane >> 4;
    const int h = blockIdx.y;
    const int q0 = blockIdx.x * 64;

    const int qrow = q0 + wv * 16 + l15;
    bf16x8 qf[2];
    #pragma unroll
    for (int kk = 0; kk < 2; ++kk)
        qf[kk] = *(const bf16x8*)(qkv + (size_t)qrow * QKVN + h * 64 + kk * 32 + g * 8);

    f32x4 o[4];
    #pragma unroll
    for (int n = 0; n < 4; ++n)
        #pragma unroll
        for (int e = 0; e < 4; ++e) o[n][e] = 0.f;
    float mst[4] = {-3e38f, -3e38f, -3e38f, -3e38f};
    float lst[4] = {0.f, 0.f, 0.f, 0.f};

    const int srow = tid >> 3;
    const int scol = (tid & 7) * 8;
    const int xr  = (l15 & 7) << 3;
    const int kg4 = (tid >> 4) * 4;
    const int dg4 = (tid & 15) * 4;

    for (int c = 0; c < 9; ++c) {
        const int kc = q0 - 256 + c * 64;
        if (kc + 64 <= 0 || kc >= S_LEN) continue;   // fully masked chunk: exact no-op
        const bool fast = (kc >= 0) && (kc + 64 <= S_LEN) && (c >= 1) && (c <= 7);
        __syncthreads();
        #pragma unroll
        for (int cc = 0; cc < 2; ++cc) {
            const int r = cc * 32 + srow;
            int krow = min(max(kc + r, 0), S_LEN - 1);
            gload16(qkv + (size_t)krow * QKVN + DMODEL + h * 64 + (scol ^ ((r & 7) << 3)),
                    (char*)Ks + cc * 4096 + wv * 1024);
        }
        {
            u16x4 vr[4];
            #pragma unroll
            for (int j = 0; j < 4; ++j) {
                int vrow = min(max(kc + kg4 + j, 0), S_LEN - 1);
                vr[j] = *(const u16x4*)(qkv + (size_t)vrow * QKVN + 2 * DMODEL + h * 64 + dg4);
            }
            #pragma unroll
            for (int i = 0; i < 4; ++i) {
                const int d = dg4 + i;
                const int f = ((d >> 3) ^ d) & 7;
                u16x4 w;
                w[0] = vr[0][i]; w[1] = vr[1][i]; w[2] = vr[2][i]; w[3] = vr[3][i];
                *(u16x4*)(Vt + d * 64 + (kg4 ^ (f << 3))) = w;
            }
        }
        __syncthreads();

        f32x4 s[4];
        #pragma unroll
        for (int n = 0; n < 4; ++n)
            #pragma unroll
            for (int e = 0; e < 4; ++e) s[n][e] = 0.f;
        __builtin_amdgcn_s_setprio(1);
        #pragma unroll
        for (int kk = 0; kk < 2; ++kk) {
            #pragma unroll
            for (int n = 0; n < 4; ++n) {
                bf16x8 kf = *(const bf16x8*)(Ks + (n * 16 + l15) * 64 + ((kk * 32 + g * 8) ^ xr));
                s[n] = __builtin_amdgcn_mfma_f32_16x16x32_bf16(qf[kk], kf, s[n], 0, 0, 0);
            }
        }
        __builtin_amdgcn_s_setprio(0);

        float pv[4][4];
        const int qbase = q0 + wv * 16 + g * 4;
        if (fast) {
            #pragma unroll
            for (int n = 0; n < 4; ++n) {
                const int key = kc + n * 16 + l15;
                const int mv = msk[key];
                #pragma unroll
                for (int r = 0; r < 4; ++r)
                    pv[n][r] = mv ? s[n][r] * 0.125f : -1e9f;
            }
        } else {
            #pragma unroll
            for (int n = 0; n < 4; ++n) {
                const int key = kc + n * 16 + l15;
                const bool kin = (key >= 0) && (key < S_LEN);
                const int mv = kin ? msk[key] : 0;
                #pragma unroll
                for (int r = 0; r < 4; ++r) {
                    const int qa = qbase + r;
                    const bool valid = (mv != 0) && (abs(key - qa) <= WIN);
                    pv[n][r] = valid ? s[n][r] * 0.125f : -1e9f;
                }
            }
        }
        float scold[4];
        #pragma unroll
        for (int r = 0; r < 4; ++r) {
            float mx = fmaxf(fmaxf(pv[0][r], pv[1][r]), fmaxf(pv[2][r], pv[3][r]));
            mx = fmaxf(mx, __shfl_xor(mx, 1));
            mx = fmaxf(mx, __shfl_xor(mx, 2));
            mx = fmaxf(mx, __shfl_xor(mx, 4));
            mx = fmaxf(mx, __shfl_xor(mx, 8));
            const float nm = fmaxf(mst[r], mx);
            scold[r] = __expf(mst[r] - nm);
            float sum = 0.f;
            #pragma unroll
            for (int n = 0; n < 4; ++n) { pv[n][r] = __expf(pv[n][r] - nm); sum += pv[n][r]; }
            sum += __shfl_xor(sum, 1); sum += __shfl_xor(sum, 2);
            sum += __shfl_xor(sum, 4); sum += __shfl_xor(sum, 8);
            lst[r] = lst[r] * scold[r] + sum;
            mst[r] = nm;
        }
        #pragma unroll
        for (int n = 0; n < 4; ++n)
            #pragma unroll
            for (int r = 0; r < 4; ++r)
                o[n][r] *= scold[r];

        #pragma unroll
        for (int n = 0; n < 4; ++n)
            #pragma unroll
            for (int r = 0; r < 4; ++r) {
                const int ql = g * 4 + r;
                Ps[wv][ql * 64 + ((n * 16 + l15) ^ ((ql & 7) << 3))] = f2bf(pv[n][r]);
            }

        __builtin_amdgcn_s_setprio(1);
        #pragma unroll
        for (int kk = 0; kk < 2; ++kk) {
            bf16x8 pf = *(const bf16x8*)(Ps[wv] + l15 * 64 + ((kk * 32 + g * 8) ^ xr));
            #pragma unroll
            for (int nd = 0; nd < 4; ++nd) {
                const int d = nd * 16 + l15;
                const int xv = (((nd * 2 + (l15 >> 3)) & 7) ^ (l15 & 7)) << 3;
                bf16x8 vf = *(const bf16x8*)(Vt + d * 64 + ((kk * 32 + g * 8) ^ xv));
                o[nd] = __builtin_amdgcn_mfma_f32_16x16x32_bf16(pf, vf, o[nd], 0, 0, 0);
            }
        }
        __builtin_amdgcn_s_setprio(0);
    }

    #pragma unroll
    for (int r = 0; r < 4; ++r) {
        const float inv = 1.0f / lst[r];
        const int qa = q0 + wv * 16 + g * 4 + r;
        #pragma unroll
        for (int nd = 0; nd < 4; ++nd)
            aout[(size_t)qa * DMODEL + h * 64 + nd * 16 + l15] = f2bf(o[nd][r] * inv);
    }
}

// ---------------- Head MLP (parallelized) ----------------
__global__ __launch_bounds__(256) void head1_kernel(const int* __restrict__ ids,
                                                    const float* __restrict__ x,
                                                    const float* __restrict__ w1,
                                                    const float* __restrict__ b1,
                                                    float* __restrict__ z1) {
    const int tid = threadIdx.x;
    __shared__ int sred[256];
    int loc = -1;
    for (int i = tid; i < S_LEN; i += 256)
        if (ids[i] == 2) loc = i;
    sred[tid] = loc;
    __syncthreads();
    for (int s2 = 128; s2; s2 >>= 1) {
        if (tid < s2) sred[tid] = max(sred[tid], sred[tid + s2]);
        __syncthreads();
    }
    const int sep = sred[0] < 0 ? (S_LEN - 1) : sred[0];

    __shared__ float emb[DMODEL];
    for (int d = tid; d < DMODEL; d += 256) emb[d] = x[(size_t)sep * DMODEL + d];
    __syncthreads();

    const int o = blockIdx.x * 64 + (tid & 63);
    const int chunk = tid >> 6;
    float s = 0.f;
    const int d0 = chunk * 192;
    for (int d = d0; d < d0 + 192; ++d)
        s += emb[d] * w1[(size_t)d * 512 + o];
    __shared__ float part[4][64];
    part[chunk][tid & 63] = s;
    __syncthreads();
    if (chunk == 0) {
        float v = part[0][tid] + part[1][tid] + part[2][tid] + part[3][tid] + b1[o];
        z1[o] = fmaxf(v, 0.f);
    }
}

__global__ __launch_bounds__(256) void head2_kernel(const float* __restrict__ z1,
                                                    const float* __restrict__ w2,
                                                    const float* __restrict__ b2,
                                                    const float* __restrict__ w3,
                                                    const float* __restrict__ b3,
                                                    float* __restrict__ out) {
    const int tid = threadIdx.x;
    __shared__ float z1s[512];
    for (int i = tid; i < 512; i += 256) z1s[i] = z1[i];
    __syncthreads();
    float s = b2[tid];
    for (int d = 0; d < 512; ++d) s += z1s[d] * w2[(size_t)d * 256 + tid];
    float z2 = fmaxf(s, 0.f);
    __shared__ float fred[256];
    fred[tid] = z2 * w3[tid];
    __syncthreads();
    for (int s2 = 128; s2; s2 >>= 1) {
        if (tid < s2) fred[tid] += fred[tid + s2];
        __syncthreads();
    }
    if (tid == 0) out[0] = tanhf(fred[0] + b3[0]);
}

// ---------------- launch ----------------

extern "C" void kernel_launch(void* const* d_in, const int* in_sizes, int n_in,
                              void* d_out, int out_size, void* d_ws, size_t ws_size,
                              hipStream_t stream) {
    const int*   ids      = (const int*)d_in[0];
    const int*   amask    = (const int*)d_in[1];
    const float* word_emb = (const float*)d_in[2];
    const float* pos_emb  = (const float*)d_in[3];
    const float* emb_s    = (const float*)d_in[4];
    const float* emb_b    = (const float*)d_in[5];
    const float* Wq = (const float*)d_in[6];
    const float* bq = (const float*)d_in[7];
    const float* Wk = (const float*)d_in[8];
    const float* bk = (const float*)d_in[9];
    const float* Wv = (const float*)d_in[10];
    const float* bv = (const float*)d_in[11];
    const float* Wo = (const float*)d_in[12];
    const float* bo = (const float*)d_in[13];
    const float* l1s = (const float*)d_in[14];
    const float* l1b = (const float*)d_in[15];
    const float* W1 = (const float*)d_in[16];
    const float* b1 = (const float*)d_in[17];
    const float* W2 = (const float*)d_in[18];
    const float* b2 = (const float*)d_in[19];
    const float* l2s = (const float*)d_in[20];
    const float* l2b = (const float*)d_in[21];
    const float* h1w = (const float*)d_in[22];
    const float* h1b = (const float*)d_in[23];
    const float* h2w = (const float*)d_in[24];
    const float* h2b = (const float*)d_in[25];
    const float* h3w = (const float*)d_in[26];
    const float* h3b = (const float*)d_in[27];

    char* ws = (char*)d_ws;
    float* x          = (float*)(ws);                              // 12.58 MB
    unsigned short* xb   = (unsigned short*)(ws + 25165824);       // 6.29 MB
    unsigned short* qkv  = (unsigned short*)(ws + 31457280);       // 18.87 MB
    unsigned short* a    = (unsigned short*)(ws + 50331648);       // 6.29 MB
    unsigned short* hb   = (unsigned short*)(ws + 56623104);       // 25.17 MB
    unsigned short* WqkvT= (unsigned short*)(ws + 81788928);       // 3.54 MB
    unsigned short* WoT  = (unsigned short*)(ws + 85327872);       // 1.18 MB
    unsigned short* W1T  = (unsigned short*)(ws + 86507520);       // 4.72 MB
    unsigned short* W2T  = (unsigned short*)(ws + 91226112);       // 4.72 MB
    float* biascat       = (float*)(ws + 95944704);                // 0.11 MB
    float* z1ws          = (float*)(ws + 96055296);                // 2 KB
    float* p12           = (float*)(ws + 100663296);               // 2x 12.58 MB contiguous split-K partials
    float* p12b          = p12 + (size_t)S_LEN * DMODEL;

    bias_concat<<<NLAYER, 256, 0, stream>>>(bq, bk, bv, biascat);
    embed_ln_kernel<<<S_LEN, 256, 0, stream>>>(ids, word_emb, pos_emb, emb_s, emb_b, x, xb);

    const size_t dd = (size_t)DMODEL * DMODEL;
    const size_t df = (size_t)DMODEL * FFDIM;

    for (int l = 0; l < NLAYER; ++l) {
        transpose_all<<<6912, 256, 0, stream>>>(Wq + l * dd, Wk + l * dd, Wv + l * dd, Wo + l * dd,
                                                W1 + l * df, W2 + l * df,
                                                WqkvT, WqkvT + dd, WqkvT + 2 * dd, WoT, W1T, W2T);

        mfma_gemm<1><<<dim3(32, 18), 256, 0, stream>>>(xb, WqkvT, biascat + (size_t)l * QKVN,
                                                       qkv, S_LEN, QKVN, DMODEL, DMODEL);
        attn_mfma<<<dim3(S_LEN / 64, NHEAD), 256, 0, stream>>>(qkv, amask, a);

        mfma_gemm<3><<<dim3(32, 6, 2), 256, 0, stream>>>(a, WoT, nullptr,
                                                         p12, S_LEN, DMODEL, 384, DMODEL);
        ln2_kernel<<<S_LEN / 4, 256, 0, stream>>>(p12, p12b, bo + (size_t)l * DMODEL, x,
                                                  l1s + (size_t)l * DMODEL, l1b + (size_t)l * DMODEL,
                                                  x, xb);

        mfma_gemm<2><<<dim3(32, 24), 256, 0, stream>>>(xb, W1T, b1 + (size_t)l * FFDIM,
                                                       hb, S_LEN, FFDIM, DMODEL, DMODEL);
        mfma_gemm<3><<<dim3(32, 6, 2), 256, 0, stream>>>(hb, W2T, nullptr,
                                                         p12, S_LEN, DMODEL, 1536, FFDIM);
        ln2_kernel<<<S_LEN / 4, 256, 0, stream>>>(p12, p12b, b2 + (size_t)l * DMODEL, x,
                                                  l2s + (size_t)l * DMODEL, l2b + (size_t)l * DMODEL,
                                                  x, xb);
    }

    head1_kernel<<<8, 256, 0, stream>>>(ids, x, h1w, h1b, z1ws);
    head2_kernel<<<1, 256, 0, stream>>>(z1ws, h2w, h2b, h3w, h3b, (float*)d_out);
}